// Round 2
// baseline (45925.586 us; speedup 1.0000x reference)
//
#include <hip/hip_runtime.h>

typedef _Float16 f16;
typedef f16 f16x2 __attribute__((ext_vector_type(2)));
typedef f16 f16x4 __attribute__((ext_vector_type(4)));
typedef f16 f16x8 __attribute__((ext_vector_type(8)));
typedef float f32x4 __attribute__((ext_vector_type(4)));
typedef unsigned int u32;
typedef unsigned long long u64;

#define R 4096
#define IN_DIM 256
#define T_STEPS 4096
#define NBLK 256
#define TPB 1024
#define WPB 16   // waves per block = rows per block

// ---- W f32 -> fp16 conversion (re-run every call; deterministic) ----
__global__ void wconv_kernel(const float* __restrict__ W, f16* __restrict__ Wh) {
    size_t i = ((size_t)blockIdx.x * 256 + threadIdx.x) * 4;
    f32x4 v = *(const f32x4*)(W + i);
    f16x4 o = { (f16)v.x, (f16)v.y, (f16)v.z, (f16)v.w };
    *(f16x4*)(Wh + i) = o;
}

// ---- persistent scan: 256 blocks x 16 waves, 1 row/wave, W row in VGPRs ----
__global__ __launch_bounds__(TPB, 4) void esn_kernel(
    const float* __restrict__ x,      // [T][256]
    const float* __restrict__ Win,    // [R][256]
    const f16*   __restrict__ W,      // [R][R] fp16
    f16* hbuf0, f16* hbuf1,           // [R] fp16 state, double-buffered (zeroed)
    u32* flags,                       // [NBLK] monotone publish counters (zeroed)
    const float* __restrict__ Wout,   // [256][R]
    const float* __restrict__ bias,   // [256]
    float* __restrict__ out)          // [256]
{
    __shared__ f16   h_lds[R];        // 8 KB staged h
    __shared__ float x_lds[IN_DIM];
    __shared__ float red[WPB];

    const int tid  = threadIdx.x;
    const int b    = blockIdx.x;
    const int wave = tid >> 6;
    const int lane = tid & 63;
    const int row  = b * WPB + wave;

    // ---- one-time preload: W row (32 VGPRs) + Win row fragment (4 VGPRs) ----
    f16x8 wreg[8];
    {
        const f16* wrow = W + (size_t)row * R;
#pragma unroll
        for (int c = 0; c < 8; ++c)
            wreg[c] = *(const f16x8*)(wrow + (c * 64 + lane) * 8);
    }
    const f32x4 winreg = *(const f32x4*)(Win + (size_t)row * IN_DIM + lane * 4);

    for (int t = 0; t < T_STEPS; ++t) {
        // ---- wait: all 256 producers published step t (flags monotone) ----
        if (t > 0 && wave == 0) {
            const u32 tgt = (u32)t;
            for (;;) {
                u32 f0 = __hip_atomic_load(flags + lane,        __ATOMIC_RELAXED, __HIP_MEMORY_SCOPE_AGENT);
                u32 f1 = __hip_atomic_load(flags + 64  + lane,  __ATOMIC_RELAXED, __HIP_MEMORY_SCOPE_AGENT);
                u32 f2 = __hip_atomic_load(flags + 128 + lane,  __ATOMIC_RELAXED, __HIP_MEMORY_SCOPE_AGENT);
                u32 f3 = __hip_atomic_load(flags + 192 + lane,  __ATOMIC_ACQUIRE, __HIP_MEMORY_SCOPE_AGENT);
                bool ok = (f0 >= tgt) & (f1 >= tgt) & (f2 >= tgt) & (f3 >= tgt);
                if (__all(ok)) break;
            }
        }
        __syncthreads();

        const f16* h_in  = (t & 1) ? hbuf1 : hbuf0;
        f16*       h_out = (t & 1) ? hbuf0 : hbuf1;

        // ---- stage h_in (8 KB) + x[t] (1 KB) into LDS ----
        {
            u64 v = __hip_atomic_load((const u64*)h_in + tid, __ATOMIC_RELAXED,
                                      __HIP_MEMORY_SCOPE_AGENT);
            *((u64*)h_lds + tid) = v;
        }
        if (tid < IN_DIM) x_lds[tid] = x[(size_t)t * IN_DIM + tid];
        __syncthreads();

        // ---- dot(W[row,:], h): 8 ds_read_b128 + 32 fdot2, W from VGPRs ----
        float acc = 0.f;
#pragma unroll
        for (int c = 0; c < 8; ++c) {
            f16x8 hv = *(const f16x8*)(h_lds + (c * 64 + lane) * 8);
#pragma unroll
            for (int k = 0; k < 4; ++k) {
                f16x2 a2 = { wreg[c][2 * k], wreg[c][2 * k + 1] };
                f16x2 b2 = { hv[2 * k],      hv[2 * k + 1] };
                acc = __builtin_amdgcn_fdot2(a2, b2, acc, false);
            }
        }
        // fused input projection
        {
            const f32x4 xv = *(const f32x4*)(&x_lds[lane * 4]);
            acc = fmaf(winreg.x, xv.x, acc);
            acc = fmaf(winreg.y, xv.y, acc);
            acc = fmaf(winreg.z, xv.z, acc);
            acc = fmaf(winreg.w, xv.w, acc);
        }
        // wave-64 butterfly reduce
#pragma unroll
        for (int off = 32; off > 0; off >>= 1)
            acc += __shfl_xor(acc, off, 64);

        if (lane == 0) red[wave] = tanhf(acc);
        __syncthreads();

        // ---- publish: 16 rows as fp16 (32 B), then release flag ----
        if (tid < 4) {
            f16x4 pv = { (f16)red[tid * 4 + 0], (f16)red[tid * 4 + 1],
                         (f16)red[tid * 4 + 2], (f16)red[tid * 4 + 3] };
            u64 bits;
            __builtin_memcpy(&bits, &pv, 8);
            __hip_atomic_store((u64*)(h_out + b * WPB) + tid, bits,
                               __ATOMIC_RELAXED, __HIP_MEMORY_SCOPE_AGENT);
        }
        if (tid == 0) {
            // RELEASE drains this wave's vmcnt -> h stores at L3 before flag
            __hip_atomic_store(flags + b, (u32)(t + 1), __ATOMIC_RELEASE,
                               __HIP_MEMORY_SCOPE_AGENT);
        }
        // no trailing barrier needed: next iteration's poll + __syncthreads
        // holds everyone until step t+1 data is globally visible
    }

    // ---- epilogue: wait for final h, compute out = Wout @ h_T + b ----
    if (wave == 0) {
        const u32 tgt = (u32)T_STEPS;
        for (;;) {
            u32 f0 = __hip_atomic_load(flags + lane,        __ATOMIC_RELAXED, __HIP_MEMORY_SCOPE_AGENT);
            u32 f1 = __hip_atomic_load(flags + 64  + lane,  __ATOMIC_RELAXED, __HIP_MEMORY_SCOPE_AGENT);
            u32 f2 = __hip_atomic_load(flags + 128 + lane,  __ATOMIC_RELAXED, __HIP_MEMORY_SCOPE_AGENT);
            u32 f3 = __hip_atomic_load(flags + 192 + lane,  __ATOMIC_ACQUIRE, __HIP_MEMORY_SCOPE_AGENT);
            bool ok = (f0 >= tgt) & (f1 >= tgt) & (f2 >= tgt) & (f3 >= tgt);
            if (__all(ok)) break;
        }
    }
    __syncthreads();
    {
        const f16* hf = hbuf0;  // T even -> final state in buffer 0
        u64 v = __hip_atomic_load((const u64*)hf + tid, __ATOMIC_RELAXED,
                                  __HIP_MEMORY_SCOPE_AGENT);
        *((u64*)h_lds + tid) = v;
    }
    __syncthreads();
    {
        const float* worow = Wout + (size_t)b * R;
        const f32x4 wv = *(const f32x4*)(worow + tid * 4);
        float acc = wv.x * (float)h_lds[tid * 4 + 0]
                  + wv.y * (float)h_lds[tid * 4 + 1]
                  + wv.z * (float)h_lds[tid * 4 + 2]
                  + wv.w * (float)h_lds[tid * 4 + 3];
#pragma unroll
        for (int off = 32; off > 0; off >>= 1)
            acc += __shfl_xor(acc, off, 64);
        if (lane == 0) red[wave] = acc;
        __syncthreads();
        if (tid == 0) {
            float s = bias[b];
#pragma unroll
            for (int w = 0; w < WPB; ++w) s += red[w];
            out[b] = s;
        }
    }
}

extern "C" void kernel_launch(void* const* d_in, const int* in_sizes, int n_in,
                              void* d_out, int out_size, void* d_ws, size_t ws_size,
                              hipStream_t stream) {
    const float* x    = (const float*)d_in[0];
    const float* Win  = (const float*)d_in[1];
    const float* W    = (const float*)d_in[2];
    const float* Wout = (const float*)d_in[3];
    const float* bias = (const float*)d_in[4];
    float* out = (float*)d_out;

    char* ws = (char*)d_ws;
    u32* flags = (u32*)ws;                 // 1 KB @ 0
    f16* h0    = (f16*)(ws + 8192);        // 8 KB
    f16* h1    = (f16*)(ws + 16384);       // 8 KB
    f16* Wh    = (f16*)(ws + 65536);       // 32 MB

    // zero flags + h buffers every call (graph-capturable memset node)
    hipMemsetAsync(ws, 0, 65536, stream);

    wconv_kernel<<<(R * (size_t)R) / (256 * 4), 256, 0, stream>>>(W, Wh);
    esn_kernel<<<NBLK, TPB, 0, stream>>>(x, Win, Wh, h0, h1, flags,
                                         Wout, bias, out);
}